// Round 1
// baseline (891.605 us; speedup 1.0000x reference)
//
#include <hip/hip_runtime.h>
#include <math.h>

// Problem: y = LayerNorm( irfft(rfft(x, axis=S, ortho) * w, ortho) + x )
// B=32, S=2048, H=1024, fp32.
// Identities used:
//   x + irfft(rfft(x)*w) = irfft(rfft(x)*(w+1))          (ortho: irfft∘rfft = id)
//   irfft_o(rfft_o(x)*w) = unnorm-IFFT(unnorm-FFT(x)*w)/N (fold 1/N into weight)
// So: h = IFFT_full( FFT(z) spectral-unpack * (w+1)/N ), two h-channels packed
// per complex FFT (two-for-one). DC/Nyquist imag parts dropped (pocketfft c2r).

#define PI_F 3.14159265358979323846f
#define SW(c) ((c) ^ (((c) >> 4) & 15))   // LDS bank de-conflict swizzle (bijective on [0,2048))

__device__ __forceinline__ float2 cadd(float2 a, float2 b){ return make_float2(a.x+b.x, a.y+b.y); }
__device__ __forceinline__ float2 csub(float2 a, float2 b){ return make_float2(a.x-b.x, a.y-b.y); }
__device__ __forceinline__ float2 cmul(float2 a, float2 b){ return make_float2(a.x*b.x - a.y*b.y, a.x*b.y + a.y*b.x); }

// ---- fused double radix-2 DIF stage (lens L and L/2), natural->bitrev order ----
template<int L>
__device__ __forceinline__ void fwd_stage(float2* A, int j){
  constexpr int half = L >> 1;
  const float ang0 = -PI_F / (float)L;
  #pragma unroll
  for (int r = 0; r < 4; ++r){
    int g    = j + (r << 7);          // 512 groups, 128 threads
    int blk  = g / half;
    int joff = g - blk * half;
    int i0   = blk * (2 * L) + joff;
    float2 u0 = A[SW(i0)];
    float2 u1 = A[SW(i0 + half)];
    float2 u2 = A[SW(i0 + L)];
    float2 u3 = A[SW(i0 + L + half)];
    float sn, cs; __sincosf(ang0 * (float)joff, &sn, &cs);
    float2 w1 = make_float2(cs, sn);           // e^{-i pi joff / L}
    float2 t0  = cadd(u0, u2);
    float2 d02 = csub(u0, u2);
    float2 t1  = cadd(u1, u3);
    float2 d13 = csub(u1, u3);
    float2 t2  = cmul(d02, w1);
    float2 tm  = cmul(d13, w1);
    float2 t3  = make_float2(tm.y, -tm.x);     // * (-i)
    float2 w2  = cmul(w1, w1);                 // e^{-i 2pi joff / L}
    A[SW(i0)]            = cadd(t0, t1);
    A[SW(i0 + half)]     = cmul(csub(t0, t1), w2);
    A[SW(i0 + L)]        = cadd(t2, t3);
    A[SW(i0 + L + half)] = cmul(csub(t2, t3), w2);
  }
}

// ---- fused double radix-2 DIT stage (lens l and 2l), bitrev->natural, +i twiddles ----
template<int l>
__device__ __forceinline__ void inv_stage(float2* A, int j){
  const float angB = PI_F / (float)(2 * l);
  #pragma unroll
  for (int r = 0; r < 4; ++r){
    int g    = j + (r << 7);
    int blk  = g / l;
    int joff = g - blk * l;
    int base = blk * (4 * l);
    int i0 = base + joff;
    float2 u0 = A[SW(i0)];
    float2 u1 = A[SW(i0 + l)];
    float2 u2 = A[SW(i0 + 2*l)];
    float2 u3 = A[SW(i0 + 3*l)];
    float sn, cs; __sincosf(angB * (float)joff, &sn, &cs);
    float2 wB = make_float2(cs, sn);           // e^{+i pi joff / 2l}
    float2 w  = cmul(wB, wB);                  // e^{+i pi joff / l}
    float2 a1 = cmul(u1, w);
    float2 b0 = cadd(u0, a1), b1 = csub(u0, a1);
    float2 a3 = cmul(u3, w);
    float2 b2 = cadd(u2, a3), b3 = csub(u2, a3);
    float2 t2 = cmul(b2, wB);
    float2 c0 = cadd(b0, t2), c2 = csub(b0, t2);
    float2 iwB = make_float2(-wB.y, wB.x);     // i * wB
    float2 t3 = cmul(b3, iwB);
    float2 c1 = cadd(b1, t3), c3 = csub(b1, t3);
    A[SW(i0)]       = c0;
    A[SW(i0 + l)]   = c1;
    A[SW(i0 + 2*l)] = c2;
    A[SW(i0 + 3*l)] = c3;
  }
}

__device__ __forceinline__ float2 fetchW(const float2* __restrict__ wT,
                                         const float2* __restrict__ cw,
                                         int useT, int h, int k){
  if (useT) return wT[(size_t)h * 1025 + k];
  float2 w = cw[(size_t)k * 1024 + h];
  const float inv = 1.0f / 2048.0f;
  return make_float2((w.x + 1.0f) * inv, w.y * inv);
}

// ---- weight prep: wT[h][k] = (cw[k][h] + 1) / 2048, tiled transpose ----
__global__ void prep_w_kernel(const float2* __restrict__ cw, float2* __restrict__ wT){
  __shared__ float2 tile[32][33];
  int k0 = blockIdx.x * 32, h0 = blockIdx.y * 32;
  int tx = threadIdx.x, ty = threadIdx.y;   // 32 x 8
  #pragma unroll
  for (int r = 0; r < 4; ++r){
    int k = k0 + ty + 8 * r;
    if (k < 1025) tile[ty + 8*r][tx] = cw[(size_t)k * 1024 + (h0 + tx)];
  }
  __syncthreads();
  const float inv = 1.0f / 2048.0f;
  #pragma unroll
  for (int r = 0; r < 4; ++r){
    int h = h0 + ty + 8 * r;
    int k = k0 + tx;
    if (k < 1025){
      float2 w = tile[tx][ty + 8*r];
      wT[(size_t)h * 1025 + k] = make_float2((w.x + 1.0f) * inv, w.y * inv);
    }
  }
}

// ---- main FFT filter kernel: 4 channel-pairs per WG, 512 threads ----
__global__ __launch_bounds__(512) void fft_filter_kernel(
    const float2* __restrict__ x,    // [B,S,H/2] as float2 (pairs of h)
    const float2* __restrict__ cw,   // raw weights [1025,1024] float2
    const float2* __restrict__ wT,   // transposed weights [1024][1025] or null
    int useT,
    float2* __restrict__ out){
  __shared__ float2 lds[4][2048];    // exactly 64 KB
  const int t  = threadIdx.x;
  const int bx = blockIdx.x;
  const int b  = bx >> 7;            // 128 WGs per batch
  const int pg = bx & 127;           // pair-group: pairs 4*pg .. 4*pg+3
  const int f  = t >> 7;             // which FFT (0..3)
  const int j  = t & 127;            // worker id within FFT
  float2* A = lds[f];

  // load: z_s = x[b,s,2P] + i x[b,s,2P+1]
  {
    const int p4 = t & 3, srow = t >> 2;
    const size_t base = ((size_t)b * 2048) * 512 + (size_t)(pg * 4 + p4);
    #pragma unroll
    for (int it = 0; it < 16; ++it){
      int s = srow + (it << 7);
      lds[p4][SW(s)] = x[base + (size_t)s * 512];
    }
  }
  __syncthreads();

  // forward DIF: lens 1024..2 (fused pairs), then len=1
  fwd_stage<1024>(A, j); __syncthreads();
  fwd_stage<256>(A, j);  __syncthreads();
  fwd_stage<64>(A, j);   __syncthreads();
  fwd_stage<16>(A, j);   __syncthreads();
  fwd_stage<4>(A, j);    __syncthreads();
  #pragma unroll
  for (int r = 0; r < 8; ++r){
    int m = j + (r << 7);
    int ia = SW(2*m), ib = SW(2*m + 1);
    float2 u = A[ia], v = A[ib];
    A[ia] = cadd(u, v);
    A[ib] = csub(u, v);
  }
  __syncthreads();

  // spectral step: unpack two real spectra, multiply by (w+1)/N, repack Hermitian
  {
    const int hA = (pg << 3) + (f << 1);   // even channel of this FFT
    if (j == 0){
      // k = 0 at pos 0; k = 1024 (Nyquist) at pos br(1024)=1. Drop imag parts (c2r).
      float2 z0 = A[0];
      float2 wa = fetchW(wT, cw, useT, hA, 0);
      float2 wb = fetchW(wT, cw, useT, hA + 1, 0);
      A[0] = make_float2(z0.x * wa.x, z0.y * wb.x);
      int p1 = SW(1);
      float2 zn = A[p1];
      wa = fetchW(wT, cw, useT, hA, 1024);
      wb = fetchW(wT, cw, useT, hA + 1, 1024);
      A[p1] = make_float2(zn.x * wa.x, zn.y * wb.x);
    }
    #pragma unroll
    for (int r = 0; r < 8; ++r){
      int k = 1 + j + (r << 7);
      if (k < 1024){
        int kr = 2048 - k;
        int p1 = SW((int)(__brev((unsigned)k) >> 21));
        int p2 = SW((int)(__brev((unsigned)kr) >> 21));
        float2 Z1 = A[p1], Z2 = A[p2];
        float2 Xa = make_float2(0.5f*(Z1.x + Z2.x), 0.5f*(Z1.y - Z2.y));
        float2 Xb = make_float2(0.5f*(Z1.y + Z2.y), 0.5f*(Z2.x - Z1.x));
        float2 wa = fetchW(wT, cw, useT, hA, k);
        float2 wb = fetchW(wT, cw, useT, hA + 1, k);
        float2 Ya = cmul(Xa, wa);
        float2 Yb = cmul(Xb, wb);
        A[p1] = make_float2(Ya.x - Yb.y, Ya.y + Yb.x);        // V_k
        A[p2] = make_float2(Ya.x + Yb.y, Yb.x - Ya.y);        // V_{N-k} = conj pack
      }
    }
  }
  __syncthreads();

  // inverse DIT: len=1, then fused lens 2..1024
  #pragma unroll
  for (int r = 0; r < 8; ++r){
    int m = j + (r << 7);
    int ia = SW(2*m), ib = SW(2*m + 1);
    float2 u = A[ia], v = A[ib];
    A[ia] = cadd(u, v);
    A[ib] = csub(u, v);
  }
  __syncthreads();
  inv_stage<2>(A, j);   __syncthreads();
  inv_stage<8>(A, j);   __syncthreads();
  inv_stage<32>(A, j);  __syncthreads();
  inv_stage<128>(A, j); __syncthreads();
  inv_stage<512>(A, j); __syncthreads();

  // store: natural order, (Re,Im) = channels (2P, 2P+1) = h = filtered + residual
  {
    const int p4 = t & 3, srow = t >> 2;
    const size_t base = ((size_t)b * 2048) * 512 + (size_t)(pg * 4 + p4);
    #pragma unroll
    for (int it = 0; it < 16; ++it){
      int s = srow + (it << 7);
      out[base + (size_t)s * 512] = lds[p4][SW(s)];
    }
  }
}

// ---- LayerNorm over H=1024, in place on d_out ----
__global__ __launch_bounds__(256) void ln_kernel(float* __restrict__ io,
                                                 const float* __restrict__ gma,
                                                 const float* __restrict__ bta){
  const int row = blockIdx.x;
  const int t = threadIdx.x;
  float4* r4 = (float4*)io + (size_t)row * 256;
  float4 v = r4[t];
  float s1 = v.x + v.y + v.z + v.w;
  float s2 = v.x*v.x + v.y*v.y + v.z*v.z + v.w*v.w;
  #pragma unroll
  for (int off = 32; off > 0; off >>= 1){
    s1 += __shfl_down(s1, off);
    s2 += __shfl_down(s2, off);
  }
  __shared__ float red[8];
  __shared__ float mr[2];
  const int wid = t >> 6, lane = t & 63;
  if (lane == 0){ red[wid] = s1; red[4 + wid] = s2; }
  __syncthreads();
  if (t == 0){
    float ts1 = red[0] + red[1] + red[2] + red[3];
    float ts2 = red[4] + red[5] + red[6] + red[7];
    float mean = ts1 * (1.0f / 1024.0f);
    float var  = ts2 * (1.0f / 1024.0f) - mean * mean;
    mr[0] = mean;
    mr[1] = rsqrtf(fmaxf(var, 0.0f) + 1e-12f);
  }
  __syncthreads();
  const float mean = mr[0], rstd = mr[1];
  const float4 gv = ((const float4*)gma)[t];
  const float4 bv = ((const float4*)bta)[t];
  float4 o;
  o.x = (v.x - mean) * rstd * gv.x + bv.x;
  o.y = (v.y - mean) * rstd * gv.y + bv.y;
  o.z = (v.z - mean) * rstd * gv.z + bv.z;
  o.w = (v.w - mean) * rstd * gv.w + bv.w;
  r4[t] = o;
}

extern "C" void kernel_launch(void* const* d_in, const int* in_sizes, int n_in,
                              void* d_out, int out_size, void* d_ws, size_t ws_size,
                              hipStream_t stream){
  const float2* x2  = (const float2*)d_in[0];
  const float2* cw2 = (const float2*)d_in[1];
  const float*  gma = (const float*)d_in[2];
  const float*  bta = (const float*)d_in[3];
  float2* out2 = (float2*)d_out;
  float*  outf = (float*)d_out;

  const int Bn = in_sizes[0] / (2048 * 1024);   // 32

  const size_t needW = (size_t)1025 * 1024 * sizeof(float2);
  const int useT = (ws_size >= needW) ? 1 : 0;
  float2* wT = (float2*)d_ws;

  if (useT){
    hipLaunchKernelGGL(prep_w_kernel, dim3(33, 32), dim3(32, 8), 0, stream, cw2, wT);
  }
  hipLaunchKernelGGL(fft_filter_kernel, dim3(Bn * 128), dim3(512), 0, stream,
                     x2, cw2, wT, useT, out2);
  hipLaunchKernelGGL(ln_kernel, dim3(Bn * 2048), dim3(256), 0, stream,
                     outf, gma, bta);
}